// Round 10
// baseline (348.078 us; speedup 1.0000x reference)
//
#include <hip/hip_runtime.h>
#include <cmath>

// INGP hashgrid encode — R15: slotted Morton binning (R14) + coarse levels
// FUSED into the fine dispatch, finish reduced to a pure assembler.
//   Ledger (R14, total 309): OH ~72 (harness, unattackable) | memset+scatter
//   ~14 | fine 107 (AT per-XCD L2 lookup floor, 31G/s/XCD) | finish ~78
//   (43 coarse lookups + 35 assemble) | gaps ~38.
//   R15 mechanism: fine is L2-TAG-THROUGHPUT-bound, coarse (post-sort) is
//   latency/VALU/L1-bound -> different pipes, co-scheduling overlaps (m114:
//   time ~= max, not sum). Octet-interleaved grid 4 fine : 1 coarse keeps
//   fine's blockIdx%8 XCD pinning intact (fine blocks' b&7 unchanged).
//   Coarse block = 256 slots, 8 levels in-register, LDS transpose, writes
//   OUT LINE 0 directly (4 lanes x vf4 = one full 64B single-owner line per
//   instruction — the R9/R12-proven clean pattern; R11's amplification came
//   from per-thread row stores, 64 partial lines per instruction).
//   finish: 8 ws streams + slots.w -> LDS -> OUT LINE 1 (same pattern).
//   CAP 24->20: slots 851968 -> 720896, ws 54.5 -> 46MB (fill 73%,
//   overflow ~8.5K << 64K; adversarial inputs still exact via inline path).

constexpr int LVLS = 16;
constexpr unsigned TBL = 1u << 19;
constexpr unsigned TMASK = TBL - 1u;
constexpr unsigned P1 = 2654435761u;
constexpr unsigned P2 = 805459861u;
constexpr int NBINS = 32768;         // 32^3 Morton bins
constexpr int CAP = 20;              // slots per bin (Poisson mean 16)
constexpr int MAIN = NBINS * CAP;    // 655360 main slots
constexpr int OVCAP = 65536;         // overflow slots
constexpr int S_TOT = MAIN + OVCAP;  // 720896 = 512*1408 = 256*2816
constexpr int NFINE = S_TOT / 512;   // 1408 fine chunks (per level)
constexpr int NCOARSE = S_TOT / 256; // 2816 coarse blocks
constexpr int T_OCT = NFINE + NCOARSE / 8;   // 1408 + 352 = 1760 octets

typedef float vf2 __attribute__((ext_vector_type(2)));
typedef float vf4 __attribute__((ext_vector_type(4)));

struct ResArr { float r[LVLS]; };

__device__ __forceinline__ unsigned spread5(unsigned v) {
    v &= 31u;
    v = (v | (v << 8)) & 0x100Fu;
    v = (v | (v << 4)) & 0x10C3u;
    v = (v | (v << 2)) & 0x1249u;
    return v;
}

__device__ __forceinline__ unsigned bin_key(float px, float py, float pz) {
    float x = (px + 1.0f) * 0.5f;
    float y = (py + 1.0f) * 0.5f;
    float z = (pz + 1.0f) * 0.5f;
    unsigned bx = (unsigned)fminf(31.f, fmaxf(0.f, floorf(x * 32.f)));
    unsigned by = (unsigned)fminf(31.f, fmaxf(0.f, floorf(y * 32.f)));
    unsigned bz = (unsigned)fminf(31.f, fmaxf(0.f, floorf(z * 32.f)));
    return spread5(bx) | (spread5(by) << 1) | (spread5(bz) << 2);
}

// One level's trilinear hashed gather for normalized point (x,y,z).
__device__ __forceinline__ void level_gather(
    const float2* __restrict__ tab, float r,
    float x, float y, float z, float& f0, float& f1)
{
    float posx = x * r, posy = y * r, posz = z * r;
    float fx = floorf(posx), fy = floorf(posy), fz = floorf(posz);
    float wx = posx - fx, wy = posy - fy, wz = posz - fz;
    unsigned ix = (unsigned)fx, iy = (unsigned)fy, iz = (unsigned)fz;
    unsigned hx0 = ix, hx1 = ix + 1u;
    unsigned hy0 = iy * P1;
    unsigned hz0 = iz * P2, hz1 = hz0 + P2;

    unsigned hyz[4];
    hyz[0] = hy0 ^ hz0;
    hyz[1] = hy0 ^ hz1;
    hyz[2] = (hy0 + P1) ^ hz0;
    hyz[3] = (hy0 + P1) ^ hz1;

    float2 v[8];
    if ((ix & 1u) == 0u) {
        // x-pair idx differ by ^1 -> one aligned float4 covers both.
        #pragma unroll
        for (int yz = 0; yz < 4; ++yz) {
            unsigned b0 = (hx0 ^ hyz[yz]) & TMASK;   // x=0 corner
            vf4 qd = *(const vf4*)(tab + (b0 & ~1u));
            float2 lo = make_float2(qd.x, qd.y);
            float2 hi = make_float2(qd.z, qd.w);
            bool odd = (b0 & 1u) != 0u;
            v[yz]     = odd ? hi : lo;
            v[4 + yz] = odd ? lo : hi;
        }
    } else {
        #pragma unroll
        for (int yz = 0; yz < 4; ++yz) {
            unsigned b0 = (hx0 ^ hyz[yz]) & TMASK;
            unsigned b1 = (hx1 ^ hyz[yz]) & TMASK;
            v[yz]     = tab[b0];
            v[4 + yz] = tab[b1];
        }
    }

    float ox = 1.0f - wx, oy = 1.0f - wy, oz = 1.0f - wz;
    float w[8];
    w[0] = (ox * oy) * oz;
    w[1] = (ox * oy) * wz;
    w[2] = (ox * wy) * oz;
    w[3] = (ox * wy) * wz;
    w[4] = (wx * oy) * oz;
    w[5] = (wx * oy) * wz;
    w[6] = (wx * wy) * oz;
    w[7] = (wx * wy) * wz;

    f0 = w[0] * v[0].x;
    f1 = w[0] * v[0].y;
    #pragma unroll
    for (int c = 1; c < 8; ++c) {
        f0 += w[c] * v[c].x;
        f1 += w[c] * v[c].y;
    }
}

// Full 16-level encode for one point, row written directly (rare paths).
__device__ __forceinline__ void encode_point_direct(
    const float* __restrict__ tables, const ResArr& ra,
    float px, float py, float pz, vf4* __restrict__ row)
{
    float x = (px + 1.0f) * 0.5f;
    float y = (py + 1.0f) * 0.5f;
    float z = (pz + 1.0f) * 0.5f;
    float acc[2 * LVLS];
    #pragma unroll
    for (int l = 0; l < LVLS; ++l) {
        const float2* __restrict__ tab = (const float2*)tables + (size_t)l * TBL;
        float f0, f1;
        level_gather(tab, ra.r[l], x, y, z, f0, f1);
        acc[2 * l] = f0; acc[2 * l + 1] = f1;
    }
    #pragma unroll
    for (int k = 0; k < 8; ++k) {
        vf4 o;
        o.x = acc[4 * k + 0]; o.y = acc[4 * k + 1];
        o.z = acc[4 * k + 2]; o.w = acc[4 * k + 3];
        __builtin_nontemporal_store(o, row + k);
    }
}

// Single-pass slotted scatter. cnt[NBINS] = per-bin counters, cnt[NBINS]
// (last entry) = overflow counter.
__global__ __launch_bounds__(256) void ingp_scatter1(
    const float* __restrict__ pts, unsigned* __restrict__ cnt,
    vf4* __restrict__ slots, const float* __restrict__ tables,
    vf4* __restrict__ out, ResArr ra, int npts)
{
    int i = blockIdx.x * 256 + threadIdx.x;
    if (i >= npts) return;
    float px = pts[i * 3 + 0], py = pts[i * 3 + 1], pz = pts[i * 3 + 2];
    unsigned bin = bin_key(px, py, pz);
    unsigned pos = atomicAdd(&cnt[bin], 1u);
    vf4 o; o.x = px; o.y = py; o.z = pz; o.w = __int_as_float(i);
    if (pos < (unsigned)CAP) {
        __builtin_nontemporal_store(o, slots + (size_t)bin * CAP + pos);
    } else {
        unsigned ov = atomicAdd(&cnt[NBINS], 1u);
        if (ov < (unsigned)OVCAP) {
            __builtin_nontemporal_store(o, slots + MAIN + ov);
        } else {
            // adversarial-only fallback: encode inline, still correct
            encode_point_direct(tables, ra, px, py, pz,
                                out + (size_t)i * 8);
        }
    }
}

__device__ __forceinline__ bool slot_valid(
    const unsigned* __restrict__ cnt, int sidx)
{
    if (sidx < MAIN) {
        unsigned bin = (unsigned)sidx / (unsigned)CAP;
        unsigned within = (unsigned)sidx - bin * (unsigned)CAP;
        unsigned c = cnt[bin];
        return within < (c < (unsigned)CAP ? c : (unsigned)CAP);
    } else {
        unsigned idx = (unsigned)(sidx - MAIN);
        unsigned c = cnt[NBINS];
        return idx < (c < (unsigned)OVCAP ? c : (unsigned)OVCAP);
    }
}

// Fused dispatch: octets 0..T_OCT, oct%5==4 -> coarse, else fine.
//  fine  : level 8+(b&7) XCD-pinned, 512 slots -> ws[lvl-8][S_TOT].
//  coarse: 256 slots, levels 0-7 per thread, LDS transpose, OUT LINE 0.
__global__ __launch_bounds__(256) void ingp_fuse(
    const vf4* __restrict__ slots, const unsigned* __restrict__ cnt,
    const float* __restrict__ tables,
    float2* __restrict__ ws,          // [8][S_TOT] float2
    vf4* __restrict__ out,            // [N][8] vf4 rows (original order)
    ResArr ra)
{
    __shared__ float2 a[8][258];
    __shared__ int s_orig[256];
    int b = blockIdx.x;
    int oct = b >> 3, l8 = b & 7;
    int t = threadIdx.x;

    if (oct % 5 == 4) {
        // ---------------- coarse block ----------------
        int c = (oct / 5) * 8 + l8;              // [0, NCOARSE)
        int sidx = c * 256 + t;
        bool valid = slot_valid(cnt, sidx);
        float px = -1.0f, py = -1.0f, pz = -1.0f;
        int orig = -1;
        if (valid) {
            vf4 v = __builtin_nontemporal_load(slots + sidx);
            px = v.x; py = v.y; pz = v.z; orig = __float_as_int(v.w);
        }
        s_orig[t] = orig;
        float x = (px + 1.0f) * 0.5f;
        float y = (py + 1.0f) * 0.5f;
        float z = (pz + 1.0f) * 0.5f;
        #pragma unroll
        for (int l = 0; l < 8; ++l) {
            const float2* __restrict__ tab =
                (const float2*)tables + (size_t)l * TBL;
            float f0, f1;
            level_gather(tab, ra.r[l], x, y, z, f0, f1);
            a[l][t] = make_float2(f0, f1);
        }
        __syncthreads();
        int j = t & 3, sl = t >> 2;
        #pragma unroll
        for (int it = 0; it < 4; ++it) {
            int s = sl + it * 64;
            int og = s_orig[s];
            if (og >= 0) {
                float2 u = a[2 * j][s];
                float2 v = a[2 * j + 1][s];
                vf4 o; o.x = u.x; o.y = u.y; o.z = v.x; o.w = v.y;
                // 4 lanes cover one full 64B line (row line 0).
                __builtin_nontemporal_store(o, out + (size_t)og * 8 + j);
            }
        }
    } else {
        // ---------------- fine block ----------------
        int f = (oct / 5) * 4 + (oct % 5);       // [0, NFINE)
        int lvl = 8 + l8;                        // XCD-pinned: b%8 -> XCD
        float r = ra.r[lvl];
        const float2* __restrict__ tab =
            (const float2*)tables + (size_t)lvl * TBL;
        float2* __restrict__ wrow = ws + (size_t)l8 * S_TOT;

        #pragma unroll
        for (int s = 0; s < 2; ++s) {
            int sidx = f * 512 + t + s * 256;
            if (!slot_valid(cnt, sidx)) continue;
            vf4 v = __builtin_nontemporal_load(slots + sidx);
            float x = (v.x + 1.0f) * 0.5f;
            float y = (v.y + 1.0f) * 0.5f;
            float z = (v.z + 1.0f) * 0.5f;
            float f0, f1;
            level_gather(tab, r, x, y, z, f0, f1);
            vf2 o; o.x = f0; o.y = f1;
            __builtin_nontemporal_store(o, (vf2*)(wrow + sidx));
        }
    }
}

// Assembler: 8 fine ws streams -> OUT LINE 1 per slot (4 lanes x vf4).
__global__ __launch_bounds__(256) void ingp_finish(
    const vf4* __restrict__ slots, const unsigned* __restrict__ cnt,
    const float2* __restrict__ ws,    // [8][S_TOT] float2
    vf4* __restrict__ out)
{
    __shared__ float2 a[8][258];
    __shared__ int s_orig[256];
    int base = blockIdx.x * 256;
    int t = threadIdx.x;
    int sidx = base + t;

    bool valid = slot_valid(cnt, sidx);
    int orig = -1;
    if (valid) {
        vf4 v = __builtin_nontemporal_load(slots + sidx);
        orig = __float_as_int(v.w);
    }
    s_orig[t] = orig;

    #pragma unroll
    for (int l = 0; l < 8; ++l) {
        vf2 w = __builtin_nontemporal_load(
            (const vf2*)(ws + (size_t)l * S_TOT + sidx));
        a[l][t] = make_float2(w.x, w.y);
    }
    __syncthreads();

    int j = t & 3, sl = t >> 2;
    #pragma unroll
    for (int it = 0; it < 4; ++it) {
        int s = sl + it * 64;
        int og = s_orig[s];
        if (og >= 0) {
            float2 u = a[2 * j][s];
            float2 v = a[2 * j + 1][s];
            vf4 o; o.x = u.x; o.y = u.y; o.z = v.x; o.w = v.y;
            // 4 lanes cover one full 64B line (row line 1).
            __builtin_nontemporal_store(o, out + (size_t)og * 8 + 4 + j);
        }
    }
}

// Fallback (no usable ws): unsorted single-kernel path.
__global__ __launch_bounds__(256) void ingp_fused_raw(
    const float* __restrict__ pts,
    const float* __restrict__ tables,
    vf4* __restrict__ out, ResArr ra, int npts)
{
    int i = blockIdx.x * 256 + threadIdx.x;
    if (i >= npts) return;
    encode_point_direct(tables, ra,
                        pts[i * 3 + 0], pts[i * 3 + 1], pts[i * 3 + 2],
                        out + (size_t)i * 8);
}

extern "C" void kernel_launch(void* const* d_in, const int* in_sizes, int n_in,
                              void* d_out, int out_size, void* d_ws, size_t ws_size,
                              hipStream_t stream) {
    const float* pts    = (const float*)d_in[0];
    const float* tables = (const float*)d_in[1];
    int npts = in_sizes[0] / 3;

    // numpy-bitwise RES: GROWTH = exp((log(2048)-log(16))/15); floor(16*G**l)
    ResArr ra;
    double growth = exp((log(2048.0) - log(16.0)) / 15.0);
    for (int l = 0; l < LVLS; ++l)
        ra.r[l] = (float)floor(16.0 * pow(growth, (double)l));

    int pgrid = (npts + 255) / 256;

    // ws layout: [ws fine: 8*S_TOT float2][slots: S_TOT vf4][cnt: NBINS+1 u32]
    size_t fine_bytes = 8ull * S_TOT * sizeof(float2);        // ~46.1 MB
    size_t slot_bytes = (size_t)S_TOT * sizeof(vf4);          // ~11.5 MB
    size_t cnt_bytes  = (NBINS + 1) * sizeof(unsigned);       //  128 KB
    size_t need = fine_bytes + slot_bytes + cnt_bytes;        // ~57.8 MB

    if (ws_size >= need) {
        char* w = (char*)d_ws;
        float2*   wsf   = (float2*)w;        w += fine_bytes;
        vf4*      slots = (vf4*)w;           w += slot_bytes;
        unsigned* cnt   = (unsigned*)w;

        hipMemsetAsync(cnt, 0, cnt_bytes, stream);
        hipLaunchKernelGGL(ingp_scatter1, dim3(pgrid), dim3(256), 0, stream,
                           pts, cnt, slots, tables, (vf4*)d_out, ra, npts);
        hipLaunchKernelGGL(ingp_fuse, dim3(T_OCT * 8), dim3(256), 0, stream,
                           slots, cnt, tables, wsf, (vf4*)d_out, ra);
        hipLaunchKernelGGL(ingp_finish, dim3(S_TOT / 256), dim3(256), 0, stream,
                           slots, cnt, wsf, (vf4*)d_out);
    } else {
        hipLaunchKernelGGL(ingp_fused_raw, dim3(pgrid), dim3(256), 0, stream,
                           pts, tables, (vf4*)d_out, ra, npts);
    }
}